// Round 1
// baseline (77.326 us; speedup 1.0000x reference)
//
#include <hip/hip_runtime.h>

#define NBINS 4096
#define NCLS  20
#define CDIM  21
#define HW    (512 * 512)
#define BDIM  8
#define NPIX  (BDIM * HW)
#define CHUNKS 64
#define CHUNK  (NPIX / CHUNKS)   // 32768, divides HW -> chunk stays in one image

__global__ __launch_bounds__(256) void zero_ws(unsigned* __restrict__ w, int n) {
    int i = blockIdx.x * 256 + threadIdx.x;
    if (i < n) w[i] = 0u;
}

// Kernel 1: per-class error histograms. grid = (CHUNKS, NCLS).
__global__ __launch_bounds__(256) void lovasz_hist(const float* __restrict__ pred,
                                                   const int* __restrict__ label,
                                                   unsigned* __restrict__ g_cnt,
                                                   unsigned* __restrict__ g_pos) {
    __shared__ unsigned s_cnt[NBINS];
    __shared__ unsigned s_pos[NBINS];
    const int tid = threadIdx.x;
    for (int i = tid; i < NBINS; i += 256) { s_cnt[i] = 0u; s_pos[i] = 0u; }
    __syncthreads();

    const int cls = blockIdx.y;      // 0..19 -> class cls+1
    const int c   = cls + 1;
    const long base = (long)blockIdx.x * CHUNK;
    const int  b    = (int)(base / HW);
    const long hw0  = base - (long)b * HW;
    const float* pc = pred + ((long)b * CDIM + c) * HW + hw0;
    const int*   lb = label + base;

    for (int i = tid * 4; i < CHUNK; i += 256 * 4) {
        const float4 x = *reinterpret_cast<const float4*>(pc + i);
        const int4   l = *reinterpret_cast<const int4*>(lb + i);
#pragma unroll
        for (int j = 0; j < 4; ++j) {
            const float xv = (j == 0) ? x.x : (j == 1) ? x.y : (j == 2) ? x.z : x.w;
            const int   lv = (j == 0) ? l.x : (j == 1) ? l.y : (j == 2) ? l.z : l.w;
            float p = 1.0f / (1.0f + __expf(-xv));
            p = fminf(fmaxf(p, 1e-4f), 1.0f - 1e-4f);
            const bool  pos = (lv == c);
            const float e   = pos ? 1.0f - p : p;
            int bin = (int)(e * (float)NBINS);
            bin = bin > NBINS - 1 ? NBINS - 1 : bin;
            atomicAdd(&s_cnt[bin], 1u);
            if (pos) atomicAdd(&s_pos[bin], 1u);
        }
    }
    __syncthreads();

    unsigned* gc = g_cnt + (size_t)cls * NBINS;
    unsigned* gp = g_pos + (size_t)cls * NBINS;
    for (int i = tid; i < NBINS; i += 256) {
        const unsigned v = s_cnt[i];
        if (v) atomicAdd(&gc[i], v);
        const unsigned q = s_pos[i];
        if (q) atomicAdd(&gp[i], q);
    }
}

// Kernel 2: per-class descending prefix scan over bins + Lovasz-grad weighted sum.
// grid = NCLS blocks of 256 threads; thread t owns 16 consecutive reversed bins.
__global__ __launch_bounds__(256) void lovasz_scan(const unsigned* __restrict__ g_cnt,
                                                   const unsigned* __restrict__ g_pos,
                                                   float* __restrict__ out_pc) {
    const int cls = blockIdx.x;
    const int tid = threadIdx.x;
    constexpr int PER = NBINS / 256;  // 16

    unsigned lc[PER], lp[PER];
    unsigned csum = 0, psum = 0;
    const unsigned* gc = g_cnt + (size_t)cls * NBINS;
    const unsigned* gp = g_pos + (size_t)cls * NBINS;
#pragma unroll
    for (int j = 0; j < PER; ++j) {
        const int bin = NBINS - 1 - (tid * PER + j);  // descending error order
        lc[j] = gc[bin];
        lp[j] = gp[bin];
        csum += lc[j];
        psum += lp[j];
    }

    __shared__ unsigned sc[256], sp[256];
    sc[tid] = csum;
    sp[tid] = psum;
    __syncthreads();

    unsigned exc_c = 0, exc_p = 0, G = 0;
    for (int i = 0; i < 256; ++i) {  // tiny kernel; naive scan is fine
        const unsigned vc = sc[i], vp = sp[i];
        if (i < tid) { exc_c += vc; exc_p += vp; }
        G += vp;
    }

    float contrib = 0.0f;
    if (G > 0) {
        const float fG = (float)G;
        unsigned irun = exc_c, mrun = exc_p;
        // J(i,m) = 1 - (G-m)/(G+i-m); at i=0 this is exactly 0. All counts < 2^23, exact in f32.
        float Jprev = 1.0f - (fG - (float)mrun) / (fG + (float)(irun - mrun));
#pragma unroll
        for (int j = 0; j < PER; ++j) {
            if (lc[j]) {
                irun += lc[j];
                mrun += lp[j];
                const float Jcur = 1.0f - (fG - (float)mrun) / (fG + (float)(irun - mrun));
                const int   bin  = NBINS - 1 - (tid * PER + j);
                const float mid  = ((float)bin + 0.5f) * (1.0f / (float)NBINS);
                contrib += mid * (Jcur - Jprev);
                Jprev = Jcur;
            }
        }
    }

    __shared__ float sf[256];
    sf[tid] = contrib;
    __syncthreads();
    for (int s = 128; s > 0; s >>= 1) {
        if (tid < s) sf[tid] += sf[tid + s];
        __syncthreads();
    }
    if (tid == 0) {
        out_pc[cls * 2]     = sf[0];
        out_pc[cls * 2 + 1] = (G > 0) ? 1.0f : 0.0f;
    }
}

__global__ void lovasz_final(const float* __restrict__ out_pc, float* __restrict__ out) {
    if (threadIdx.x == 0 && blockIdx.x == 0) {
        float s = 0.0f, n = 0.0f;
        for (int c = 0; c < NCLS; ++c) {
            s += out_pc[c * 2];
            n += out_pc[c * 2 + 1];
        }
        out[0] = s / n;
    }
}

extern "C" void kernel_launch(void* const* d_in, const int* in_sizes, int n_in,
                              void* d_out, int out_size, void* d_ws, size_t ws_size,
                              hipStream_t stream) {
    const float* pred  = (const float*)d_in[0];
    const int*   label = (const int*)d_in[1];

    unsigned* g_cnt  = (unsigned*)d_ws;
    unsigned* g_pos  = g_cnt + (size_t)NCLS * NBINS;
    float*    out_pc = (float*)(g_pos + (size_t)NCLS * NBINS);
    float*    out    = (float*)d_out;

    const int nzero = NCLS * NBINS * 2;
    zero_ws<<<(nzero + 255) / 256, 256, 0, stream>>>(g_cnt, nzero);
    lovasz_hist<<<dim3(CHUNKS, NCLS), 256, 0, stream>>>(pred, label, g_cnt, g_pos);
    lovasz_scan<<<NCLS, 256, 0, stream>>>(g_cnt, g_pos, out_pc);
    lovasz_final<<<1, 64, 0, stream>>>(out_pc, out);
}